// Round 1
// baseline (392.926 us; speedup 1.0000x reference)
//
#include <hip/hip_runtime.h>
#include <hip/hip_bf16.h>
#include <stdint.h>

// ---------------------------------------------------------------------------
// SGI grid-GCN head on MI355X.  Round 5:
//  - gemm_h REWRITTEN as 256x256 8-wave 8-phase (T3/T4 counted-vmcnt dbuf +
//    T5 setprio) GEMM, batch flattened into M (16384x1536x1536), grid 384,
//    bijective XCD swizzle.  Keeps the existing conflict-free chunk-XOR
//    swizzle (measured SQ_LDS_BANK_CONFLICT=0).  Was 120.5us @ MfmaUtil 28%
//    with the 2-barrier 128^2 core; target ~70us @ ~55%.
//  - prep, gemm_o/gemm2 (128^2 core), stencil2 unchanged.
//  5 dispatches: prep, gemm_h256, gemm_o, gemm2, stencil2.
// ---------------------------------------------------------------------------

typedef __bf16 bf16;
typedef float f32x4 __attribute__((ext_vector_type(4)));
typedef bf16 bf16x8 __attribute__((ext_vector_type(8)));

#define NB 4
#define NN 4096
#define CIN 1536
#define HIDF 1536
#define OUTF 512

__device__ __forceinline__ float degree_of(int n) {
  const int x = n & 63, y = n >> 6;
  return 1.0f + (x > 0) + (x < 63) + (y > 0) + (y < 63);
}
__device__ __forceinline__ float deg2(int gx, int gy) {
  return 1.0f + (gx > 0) + (gx < 63) + (gy > 0) + (gy < 63);
}

// ------------------------------- prep ---------------------------------------
// Block = 256 threads, one 64(c) x 64(n) tile.
#define XBLK 6144
#define W1BLK 576
#define W2BLK 192

__global__ __launch_bounds__(256) void prep(
    const float* __restrict__ x, const float* __restrict__ W1,
    const float* __restrict__ W2, const float* __restrict__ Wl,
    bf16* __restrict__ xt, bf16* __restrict__ xa, bf16* __restrict__ w1t,
    bf16* __restrict__ w2t, bf16* __restrict__ wlt) {
  __shared__ float vt[64 * 64];
  __shared__ float at[64 * 64];
  const int B = blockIdx.x, t = threadIdx.x;
  const int tx = t & 15, ty = t >> 4;      // load phase: n4 = tx*4, c = ty*4+cc
  const int lane = t & 63, w = t >> 6;     // store phase
  const int u = lane & 7, n3 = lane >> 3;  // c-slot / n-subrow

  if (B < XBLK) {
    const int slot = B >> 3;
    const int nt = (B & 7) * 8 + (slot & 7);     // grid row, XCD-banded
    const int ct = (slot >> 3) % 24;
    const int bb = (slot >> 3) / 24;
    const int gy = nt;
    const int n0 = nt * 64, c0 = ct * 64;
    const float* xb = x + (long)bb * CIN * NN;
#pragma unroll
    for (int cc = 0; cc < 4; cc++) {
      const int cl = ty * 4 + cc;
      const float* row = xb + (long)(c0 + cl) * NN + n0;
      const int nb = tx * 4;
      f32x4 v = *(const f32x4*)(row + nb);
      f32x4 up = {0.f, 0.f, 0.f, 0.f};
      f32x4 dn = {0.f, 0.f, 0.f, 0.f};
      if (gy > 0) up = *(const f32x4*)(row + nb - 64);
      if (gy < 63) dn = *(const f32x4*)(row + nb + 64);
      const float lf = (tx > 0) ? row[nb - 1] : 0.f;
      const float rt = (tx < 15) ? row[nb + 4] : 0.f;
      f32x4 a;
#pragma unroll
      for (int i = 0; i < 4; i++) {
        const int gx = nb + i;
        const float degn = deg2(gx, gy);
        float s = v[i] * (1.0f / degn);
        const float lv = (i == 0) ? lf : v[i - 1];
        const float rv = (i == 3) ? rt : v[i + 1];
        if (gx > 0) s += lv * rsqrtf(degn * deg2(gx - 1, gy));
        if (gx < 63) s += rv * rsqrtf(degn * deg2(gx + 1, gy));
        if (gy > 0) s += up[i] * rsqrtf(degn * deg2(gx, gy - 1));
        if (gy < 63) s += dn[i] * rsqrtf(degn * deg2(gx, gy + 1));
        a[i] = s;
      }
      const int chunk = tx ^ (2 * ((cl >> 3) & 7));
      *(f32x4*)&vt[cl * 64 + chunk * 4] = v;
      *(f32x4*)&at[cl * 64 + chunk * 4] = a;
    }
    __syncthreads();
    bf16* xtb = xt + (long)bb * NN * CIN;
    bf16* xab = xa + (long)bb * NN * CIN;
#pragma unroll
    for (int q = 0; q < 4; q++) {
      const int j = q * 4 + w;           // 0..15
      const int arr = j & 1, r = j >> 1; // array / n-row group
      const int nl = n3 + 8 * r;
      const float* s = arr ? at : vt;
      bf16x8 o;
#pragma unroll
      for (int jj = 0; jj < 8; jj++) {
        const int cl = u * 8 + jj;
        const int col = nl ^ (8 * ((cl >> 3) & 7));
        o[jj] = (bf16)s[cl * 64 + col];
      }
      bf16* outp = arr ? xab : xtb;
      *(bf16x8*)&outp[(long)(n0 + nl) * CIN + c0 + u * 8] = o;
    }
  } else {
    // ---- weight transpose: src [K][F] fp32 -> dst [F][K] bf16 ----
    int B2 = B - XBLK;
    const float* srcp;
    bf16* dstp;
    int Fdim, Kd, nt, ct;
    if (B2 < W1BLK) {
      nt = B2 / 24; ct = B2 % 24; srcp = W1; dstp = w1t; Fdim = HIDF; Kd = CIN;
    } else if (B2 < W1BLK + W2BLK) {
      const int l = B2 - W1BLK;
      nt = l / 24; ct = l % 24; srcp = W2; dstp = w2t; Fdim = OUTF; Kd = HIDF;
    } else {
      const int l = B2 - W1BLK - W2BLK;
      nt = l / 24; ct = l % 24; srcp = Wl; dstp = wlt; Fdim = OUTF; Kd = CIN;
    }
    const int n0 = nt * 64, c0 = ct * 64;
#pragma unroll
    for (int cc = 0; cc < 4; cc++) {
      const int cl = ty * 4 + cc;
      const float* row = srcp + (long)(c0 + cl) * Fdim + n0;
      f32x4 v = *(const f32x4*)(row + tx * 4);
      const int chunk = tx ^ (2 * ((cl >> 3) & 7));
      *(f32x4*)&vt[cl * 64 + chunk * 4] = v;
    }
    __syncthreads();
#pragma unroll
    for (int q = 0; q < 2; q++) {
      const int r = q * 4 + w;           // 0..7
      const int nl = n3 + 8 * r;
      bf16x8 o;
#pragma unroll
      for (int jj = 0; jj < 8; jj++) {
        const int cl = u * 8 + jj;
        const int col = nl ^ (8 * ((cl >> 3) & 7));
        o[jj] = (bf16)vt[cl * 64 + col];
      }
      *(bf16x8*)&dstp[(long)(n0 + nl) * Kd + c0 + u * 8] = o;
    }
  }
}

// ------------------------------- GEMM core ---------------------------------
__device__ __forceinline__ void async_copy16(const void* g, void* l) {
  __builtin_amdgcn_global_load_lds(
      (const __attribute__((address_space(1))) void*)g,
      (__attribute__((address_space(3))) void*)l, 16, 0, 0);
}

struct GemmCtx {
  f32x4 acc[4][4];
  int wave, lane, wm, wn, quad, l15;
};

__device__ __forceinline__ void gemm_init(GemmCtx& cx, int t) {
  cx.wave = t >> 6;
  cx.lane = t & 63;
  cx.wm = (cx.wave & 1) * 64;
  cx.wn = (cx.wave >> 1) * 64;
  cx.quad = cx.lane >> 4;
  cx.l15 = cx.lane & 15;
#pragma unroll
  for (int i = 0; i < 4; i++)
#pragma unroll
    for (int j = 0; j < 4; j++) cx.acc[i][j] = {0.f, 0.f, 0.f, 0.f};
}

template <int K>
__device__ __forceinline__ void gemm_kloop(GemmCtx& cx, const bf16* Ab,
                                           const bf16* Bb, bf16* As,
                                           bf16* Bs) {
  const int r = cx.lane >> 3, c8 = cx.lane & 7;
  const int fchunk = c8 ^ r;
  for (int kt = 0; kt < K; kt += 64) {
#pragma unroll
    for (int i = 0; i < 4; i++) {
      const int row = i * 32 + cx.wave * 8;
      async_copy16(Ab + (long)(row + r) * K + kt + fchunk * 8, &As[row * 64]);
      async_copy16(Bb + (long)(row + r) * K + kt + fchunk * 8, &Bs[row * 64]);
    }
    __syncthreads();
#pragma unroll
    for (int kk = 0; kk < 2; kk++) {
      const int q = kk * 4 + cx.quad;
      bf16x8 af[4], bfv[4];
#pragma unroll
      for (int mr = 0; mr < 4; mr++) {
        const int m = cx.wm + mr * 16 + cx.l15;
        af[mr] = *(const bf16x8*)&As[m * 64 + (q ^ (m & 7)) * 8];
      }
#pragma unroll
      for (int nc = 0; nc < 4; nc++) {
        const int n = cx.wn + nc * 16 + cx.l15;
        bfv[nc] = *(const bf16x8*)&Bs[n * 64 + (q ^ (n & 7)) * 8];
      }
#pragma unroll
      for (int mr = 0; mr < 4; mr++)
#pragma unroll
        for (int nc = 0; nc < 4; nc++)
          cx.acc[mr][nc] = __builtin_amdgcn_mfma_f32_16x16x32_bf16(
              af[mr], bfv[nc], cx.acc[mr][nc], 0, 0, 0);
    }
    __syncthreads();
  }
}

// ----------------------- gemm_h: 256^2 8-phase core -------------------------
// h = bf16( relu(xa @ w1t^T + b1) + xt ), flattened [16384][1536].
// 512 thr / 8 waves (2M x 4N), per-wave 128x64 out, BK=64, dbuf LDS 128 KiB.
// Per K-tile: 4 phases, each {ds_read frag-set; issue 1 stage-set (2x
// global_load_lds); s_barrier; lgkmcnt(0); setprio(1); 16 MFMA; setprio(0);
// vmcnt(4); s_barrier}.  Stage sets are consumption-aligned:
//   p0: A-set0 (rows 0-63,128-191)   <- read at next-iter p0 (mh=0)
//   p1: B-set0 (even 32-row blocks)  <- read at next-iter p0 (nh=0)
//   p2: B-set1 (odd  32-row blocks)  <- read at next-iter p1 (nh=1)
//   p3: A-set1 (rows 64-127,192-255) <- read at next-iter p2 (mh=1)
// Uniform vmcnt(4) retires exactly the set staged 4 phases earlier.  Last
// iter re-stages its own tile (L2-hot) to keep the ledger uniform.
#define TS (256 * 64)

__device__ __forceinline__ void stage64(const bf16* g, bf16* l, int rowbase,
                                        int r, int fc, int kt) {
  // stages rows [rowbase, rowbase+8) of a [*, CIN] bf16 matrix, 64-col tile
  async_copy16(g + (long)(rowbase + r) * CIN + kt + fc, &l[rowbase * 64]);
}

#define LDA(mh)                                                           \
  {                                                                       \
    _Pragma("unroll") for (int kk = 0; kk < 2; kk++) {                    \
      _Pragma("unroll") for (int mr = 0; mr < 4; mr++) {                  \
        const int m = wm + (mh) * 64 + mr * 16 + l15;                     \
        const int q = kk * 4 + quad;                                      \
        af[kk][mr] = *(const bf16x8*)&As[m * 64 + ((q ^ (m & 7)) * 8)];   \
      }                                                                   \
    }                                                                     \
  }

#define LDB(dst, nh)                                                      \
  {                                                                       \
    _Pragma("unroll") for (int kk = 0; kk < 2; kk++) {                    \
      _Pragma("unroll") for (int nc = 0; nc < 2; nc++) {                  \
        const int n = wn + (nh) * 32 + nc * 16 + l15;                     \
        const int q = kk * 4 + quad;                                      \
        dst[kk][nc] = *(const bf16x8*)&Bs[n * 64 + ((q ^ (n & 7)) * 8)];  \
      }                                                                   \
    }                                                                     \
  }

#define PHASE_MFMA(mh, nh, BF)                                            \
  {                                                                       \
    _Pragma("unroll") for (int kk = 0; kk < 2; kk++) {                    \
      _Pragma("unroll") for (int mr = 0; mr < 4; mr++) {                  \
        _Pragma("unroll") for (int nc = 0; nc < 2; nc++) {                \
          acc[(mh) * 4 + mr][(nh) * 2 + nc] =                             \
              __builtin_amdgcn_mfma_f32_16x16x32_bf16(                    \
                  af[kk][mr], BF[kk][nc],                                 \
                  acc[(mh) * 4 + mr][(nh) * 2 + nc], 0, 0, 0);            \
        }                                                                 \
      }                                                                   \
    }                                                                     \
  }

#define PH_ENTER()                                  \
  __builtin_amdgcn_s_barrier();                     \
  asm volatile("s_waitcnt lgkmcnt(0)" ::: "memory");\
  __builtin_amdgcn_sched_barrier(0);                \
  __builtin_amdgcn_s_setprio(1);

#define PH_EXIT()                                   \
  __builtin_amdgcn_s_setprio(0);                    \
  __builtin_amdgcn_sched_barrier(0);                \
  asm volatile("s_waitcnt vmcnt(4)" ::: "memory");  \
  __builtin_amdgcn_s_barrier();                     \
  __builtin_amdgcn_sched_barrier(0);

__global__ __launch_bounds__(512) void gemm_h256(
    const bf16* __restrict__ xa, const bf16* __restrict__ w1t,
    const bf16* __restrict__ xt, bf16* __restrict__ h,
    const float* __restrict__ b1) {
  __shared__ bf16 sA[2 * TS];
  __shared__ bf16 sB[2 * TS];
  const int t = threadIdx.x;
  const int wave = t >> 6, lane = t & 63;
  const int quad = lane >> 4, l15 = lane & 15;
  const int wm = (wave >> 2) * 128, wn = (wave & 3) * 64;
  const int r = lane >> 3, c8 = lane & 7;
  const int fc = (c8 ^ r) * 8;
  const int w8 = wave * 8;
  const int brow = (wave >> 2) * 64 + (wave & 3) * 8;

  // bijective XCD swizzle (384 = 8*48); chunk shares the w1t n-panel in L2
  const int bid = blockIdx.x;
  const int s = (bid & 7) * 48 + (bid >> 3);
  const int mt = s & 63, nt = s >> 6;
  const int m0 = mt * 256, n0 = nt * 256;

  const bf16* Ag = xa + (long)m0 * CIN;
  const bf16* Bg = w1t + (long)n0 * CIN;

  f32x4 acc[8][4];
#pragma unroll
  for (int i = 0; i < 8; i++)
#pragma unroll
    for (int j = 0; j < 4; j++) acc[i][j] = {0.f, 0.f, 0.f, 0.f};

  bf16x8 af[2][4], bf0[2][2], bf1[2][2];

  // prologue: stage tile 0 into buffer 0 (same set order as the loop)
  stage64(Ag, sA, w8, r, fc, 0);
  stage64(Ag, sA, 128 + w8, r, fc, 0);
  stage64(Bg, sB, brow, r, fc, 0);
  stage64(Bg, sB, 128 + brow, r, fc, 0);
  stage64(Bg, sB, brow + 32, r, fc, 0);
  stage64(Bg, sB, 128 + brow + 32, r, fc, 0);
  stage64(Ag, sA, 64 + w8, r, fc, 0);
  stage64(Ag, sA, 192 + w8, r, fc, 0);
  asm volatile("s_waitcnt vmcnt(0)" ::: "memory");
  __builtin_amdgcn_s_barrier();
  __builtin_amdgcn_sched_barrier(0);

  const int NT = CIN / 64;  // 24
#pragma unroll 2
  for (int tt = 0; tt < NT; ++tt) {
    const int cu = tt & 1;
    const bf16* As = sA + cu * TS;
    const bf16* Bs = sB + cu * TS;
    bf16* Ad = sA + (cu ^ 1) * TS;
    bf16* Bd = sB + (cu ^ 1) * TS;
    // last iter re-stages its own tile: keeps the vmcnt ledger uniform
    const int ktn = ((tt + 1 < NT) ? (tt + 1) : tt) * 64;

    // ---- phase 0: reads A(mh=0) + B(nh=0); stages A-set0 ----
    LDA(0);
    LDB(bf0, 0);
    stage64(Ag, Ad, w8, r, fc, ktn);
    stage64(Ag, Ad, 128 + w8, r, fc, ktn);
    PH_ENTER();
    PHASE_MFMA(0, 0, bf0);
    PH_EXIT();

    // ---- phase 1: reads B(nh=1); stages B-set0 ----
    LDB(bf1, 1);
    stage64(Bg, Bd, brow, r, fc, ktn);
    stage64(Bg, Bd, 128 + brow, r, fc, ktn);
    PH_ENTER();
    PHASE_MFMA(0, 1, bf1);
    PH_EXIT();

    // ---- phase 2: reads A(mh=1); stages B-set1 ----
    LDA(1);
    stage64(Bg, Bd, brow + 32, r, fc, ktn);
    stage64(Bg, Bd, 128 + brow + 32, r, fc, ktn);
    PH_ENTER();
    PHASE_MFMA(1, 1, bf1);
    PH_EXIT();

    // ---- phase 3: no LDS reads (bf0 kept in regs); stages A-set1 ----
    stage64(Ag, Ad, 64 + w8, r, fc, ktn);
    stage64(Ag, Ad, 192 + w8, r, fc, ktn);
    __builtin_amdgcn_s_barrier();
    __builtin_amdgcn_sched_barrier(0);
    __builtin_amdgcn_s_setprio(1);
    PHASE_MFMA(1, 0, bf0);
    PH_EXIT();
  }

  // epilogue: h = bf16(relu(acc + b1) + xt)
#pragma unroll
  for (int MR = 0; MR < 8; MR++) {
    const int mbase = m0 + wm + (MR >> 2) * 64 + (MR & 3) * 16 + quad * 4;
#pragma unroll
    for (int NC = 0; NC < 4; NC++) {
      const int gn = n0 + wn + (NC >> 1) * 32 + (NC & 1) * 16 + l15;
      const float bv = b1[gn];
#pragma unroll
      for (int j = 0; j < 4; j++) {
        const int gm = mbase + j;
        float v = acc[MR][NC][j] + bv;
        v = v > 0.f ? v : 0.f;
        h[(long)gm * HIDF + gn] =
            (bf16)(v + (float)xt[(long)gm * HIDF + gn]);
      }
    }
  }
}

#undef LDA
#undef LDB
#undef PHASE_MFMA
#undef PH_ENTER
#undef PH_EXIT

// fp32-out GEMM (gemm_o with bias, gemm2 without).  K = 1536 both.
template <bool ADD_BIAS>
__global__ __launch_bounds__(256) void gemm_f32(
    const bf16* __restrict__ A, const bf16* __restrict__ Bw,
    float* __restrict__ C, const float* __restrict__ bias) {
  __shared__ bf16 As[128 * 64];
  __shared__ bf16 Bs[128 * 64];
  GemmCtx cx;
  gemm_init(cx, threadIdx.x);
  const int m0 = blockIdx.x * 128, n0 = blockIdx.y * 128, z = blockIdx.z;
  gemm_kloop<CIN>(cx, A + (long)z * NN * CIN + (long)m0 * CIN,
                  Bw + (long)n0 * CIN, As, Bs);
  float* Cb = C + (long)z * NN * OUTF;
#pragma unroll
  for (int mr = 0; mr < 4; mr++)
#pragma unroll
    for (int nc = 0; nc < 4; nc++) {
      const int gn = n0 + cx.wn + nc * 16 + cx.l15;
      float bv = 0.f;
      if (ADD_BIAS) bv = bias[gn];
#pragma unroll
      for (int j = 0; j < 4; j++) {
        const int gm = m0 + cx.wm + mr * 16 + cx.quad * 4 + j;
        Cb[(long)gm * OUTF + gn] = cx.acc[mr][nc][j] + bv;
      }
    }
}

// ------------------------------- stencil2 ----------------------------------
// out[b][f][n] = (Agg(G2)[n][f] + b2[f]) * Origin[n][f]; transpose via LDS.
__global__ __launch_bounds__(256) void stencil2(
    const float* __restrict__ G2, const float* __restrict__ Orig,
    const float* __restrict__ b2, float* __restrict__ out) {
  __shared__ float tile[16][513];
  const int blk = blockIdx.x;                        // 256 strips
  const int s = ((blk & 7) << 5) + (blk >> 3);       // XCD-contiguous
  const int n0 = s * 16, b = blockIdx.y;
  const int t = threadIdx.x;
  const int fq = t & 127, nl = t >> 7;
  const int f = fq * 4;
  const f32x4 bv = *(const f32x4*)(b2 + f);
#pragma unroll
  for (int p = 0; p < 8; p++) {
    const int nLoc = p * 2 + nl;
    const int n = n0 + nLoc;
    const int gx = n & 63, gy = n >> 6;
    const float degn = degree_of(n);
    const float ws = 1.0f / degn;
    const long rb = ((long)b * NN + n) * (long)OUTF + f;
    f32x4 g = *(const f32x4*)(G2 + rb);
    f32x4 a;
#pragma unroll
    for (int i = 0; i < 4; i++) a[i] = g[i] * ws;
    if (gx > 0) {
      const float w = rsqrtf(degn * degree_of(n - 1));
      f32x4 u = *(const f32x4*)(G2 + rb - OUTF);
#pragma unroll
      for (int i = 0; i < 4; i++) a[i] += u[i] * w;
    }
    if (gx < 63) {
      const float w = rsqrtf(degn * degree_of(n + 1));
      f32x4 u = *(const f32x4*)(G2 + rb + OUTF);
#pragma unroll
      for (int i = 0; i < 4; i++) a[i] += u[i] * w;
    }
    if (gy > 0) {
      const float w = rsqrtf(degn * degree_of(n - 64));
      f32x4 u = *(const f32x4*)(G2 + rb - 64L * OUTF);
#pragma unroll
      for (int i = 0; i < 4; i++) a[i] += u[i] * w;
    }
    if (gy < 63) {
      const float w = rsqrtf(degn * degree_of(n + 64));
      f32x4 u = *(const f32x4*)(G2 + rb + 64L * OUTF);
#pragma unroll
      for (int i = 0; i < 4; i++) a[i] += u[i] * w;
    }
    f32x4 og = *(const f32x4*)(Orig + rb);
#pragma unroll
    for (int i = 0; i < 4; i++) tile[nLoc][f + i] = (a[i] + bv[i]) * og[i];
  }
  __syncthreads();
  const int nl2 = t & 15, f0 = t >> 4;
#pragma unroll
  for (int q = 0; q < 32; q++) {
    const int ff = q * 16 + f0;
    out[((long)b * OUTF + ff) * (long)NN + n0 + nl2] = tile[nl2][ff];
  }
}

// ------------------------------- launcher ----------------------------------
extern "C" void kernel_launch(void* const* d_in, const int* in_sizes, int n_in,
                              void* d_out, int out_size, void* d_ws,
                              size_t ws_size, hipStream_t stream) {
  const float* x = (const float*)d_in[0];
  const float* W1 = (const float*)d_in[1];
  const float* b1 = (const float*)d_in[2];
  const float* W2 = (const float*)d_in[3];
  const float* b2 = (const float*)d_in[4];
  const float* Wl = (const float*)d_in[5];
  const float* bl = (const float*)d_in[6];
  float* out = (float*)d_out;

  uint8_t* ws = (uint8_t*)d_ws;
  size_t off = 0;
  auto alloc = [&](size_t bytes) -> void* {
    void* p = ws + off;
    off += (bytes + 255) & ~(size_t)255;
    return p;
  };
  // Lifetimes: xt [prep..gemm_o], xa [prep..gemm_h], h [gemm_h..gemm2],
  //            origin [gemm_o..stencil2] (aliases xa), g2 [gemm2..stencil2]
  //            (aliases xt).
  bf16* xt = (bf16*)alloc((size_t)NB * NN * CIN * 2);   // 50.3 MB
  bf16* xa = (bf16*)alloc((size_t)NB * NN * CIN * 2);   // 50.3 MB
  bf16* hb = (bf16*)alloc((size_t)NB * NN * HIDF * 2);  // 50.3 MB
  bf16* w1t = (bf16*)alloc((size_t)HIDF * CIN * 2);     // 4.7 MB
  bf16* w2t = (bf16*)alloc((size_t)OUTF * HIDF * 2);    // 1.6 MB
  bf16* wlt = (bf16*)alloc((size_t)OUTF * CIN * 2);     // 1.6 MB (~159 MB)
  float* origin = (float*)xa;
  float* g2 = (float*)xt;

  prep<<<XBLK + W1BLK + 2 * W2BLK, 256, 0, stream>>>(x, W1, W2, Wl, xt, xa,
                                                     w1t, w2t, wlt);
  // h = relu(xa @ W1 + b1) + xt   (batch flattened into M: 16384x1536x1536)
  gemm_h256<<<dim3((NN * NB / 256) * (HIDF / 256)), 512, 0, stream>>>(
      xa, w1t, xt, hb, b1);
  // origin = xt @ Wl + bl  (overwrites xa slot — xa dead after gemm_h)
  gemm_f32<true><<<dim3(NN / 128, OUTF / 128, NB), 256, 0, stream>>>(
      xt, wlt, origin, bl);
  // g2 = h @ W2  (overwrites xt slot — xt dead after gemm_o)
  gemm_f32<false><<<dim3(NN / 128, OUTF / 128, NB), 256, 0, stream>>>(
      hb, w2t, g2, nullptr);
  // out = (Agg(g2)+b2) * origin, transposed to [B][OUT][N]
  stencil2<<<dim3(256, NB), 256, 0, stream>>>(g2, origin, b2, out);
}